// Round 1
// baseline (1191.203 us; speedup 1.0000x reference)
//
#include <hip/hip_runtime.h>

#define BB 512
#define SS 256
#define HH 128
#define NC 10

// One block per batch row b. 256 threads: thread = (j, half), j = output unit,
// half = which 64-wide (or 14-wide for layer 0) slice of the dot it owns.
// Weights live in VGPRs (64+64 floats/thread); h and the previous-layer input
// vector live in LDS (broadcast reads, 2-way aliasing = free on gfx950).
// In-place on buf is safe: block only touches its own b-slices, and slice s is
// read (prefetched at step s-1) strictly before it is written (end of step s).
template<int DP, bool L0, bool WRITE_ALL>
__global__ __launch_bounds__(256, 2)
void scan_k(const float* __restrict__ xin,   // L0: x (B,S,DP); else buf (S,B,H)
            float* __restrict__ out,         // WRITE_ALL: buf (S,B,H); else (B,H) final h
            const float* __restrict__ w_ih,  // (H, DP)
            const float* __restrict__ w_hh,  // (H, H)
            const float* __restrict__ b_ih,
            const float* __restrict__ b_hh)
{
    constexpr int KH = HH / 2;   // 64
    constexpr int KP = DP / 2;   // 14 (layer 0) or 64
    const int b    = blockIdx.x;
    const int tid  = threadIdx.x;
    const int j    = tid >> 1;
    const int half = tid & 1;

    // ---- load weights into registers ----
    float whh[KH];
    {
        const float* wr = w_hh + j * HH + half * KH;   // 16B-aligned
        #pragma unroll
        for (int k = 0; k < KH; k += 4) {
            float4 v = *(const float4*)(wr + k);
            whh[k] = v.x; whh[k+1] = v.y; whh[k+2] = v.z; whh[k+3] = v.w;
        }
    }
    float wih[KP];
    {
        const float* wr = w_ih + j * DP + half * KP;
        if constexpr ((KP % 4) == 0) {
            #pragma unroll
            for (int k = 0; k < KP; k += 4) {
                float4 v = *(const float4*)(wr + k);
                wih[k] = v.x; wih[k+1] = v.y; wih[k+2] = v.z; wih[k+3] = v.w;
            }
        } else {
            #pragma unroll
            for (int k = 0; k < KP; k += 2) {   // KP=14, 8B-aligned
                float2 v = *(const float2*)(wr + k);
                wih[k] = v.x; wih[k+1] = v.y;
            }
        }
    }
    const float bias = b_ih[j] + b_hh[j];

    __shared__ __align__(16) float h_lds[HH];
    __shared__ __align__(16) float hp[2][DP];

    if (tid < HH) h_lds[tid] = 0.f;
    if (tid < DP) {
        hp[0][tid] = L0 ? xin[(size_t)b * SS * DP + tid]
                        : xin[(size_t)b * HH + tid];    // s = 0 slice
    }
    __syncthreads();

    int cur = 0;
    for (int s = 0; s < SS; ++s) {
        // prefetch next prev-layer vector (global, hidden behind compute)
        float pn = 0.f;
        if (s + 1 < SS && tid < DP) {
            pn = L0 ? xin[(size_t)b * SS * DP + (size_t)(s + 1) * DP + tid]
                    : xin[(size_t)(s + 1) * BB * HH + (size_t)b * HH + tid];
        }

        float a0 = 0.f, a1 = 0.f, a2 = 0.f, a3 = 0.f;
        // recurrent half-dot: h (LDS broadcast) * whh (regs)
        const float* hbase = h_lds + half * KH;
        #pragma unroll
        for (int k = 0; k < KH; k += 4) {
            float4 hv = *(const float4*)(hbase + k);
            a0 += hv.x * whh[k];
            a1 += hv.y * whh[k + 1];
            a2 += hv.z * whh[k + 2];
            a3 += hv.w * whh[k + 3];
        }
        // input-projection half-dot
        const float* pbase = &hp[cur][half * KP];
        if constexpr ((KP % 4) == 0) {
            #pragma unroll
            for (int k = 0; k < KP; k += 4) {
                float4 pv = *(const float4*)(pbase + k);
                a0 += pv.x * wih[k];
                a1 += pv.y * wih[k + 1];
                a2 += pv.z * wih[k + 2];
                a3 += pv.w * wih[k + 3];
            }
        } else {
            #pragma unroll
            for (int k = 0; k < KP; k += 2) {
                float2 pv = *(const float2*)(pbase + k);
                a0 += pv.x * wih[k];
                a1 += pv.y * wih[k + 1];
            }
        }
        float acc = (a0 + a1) + (a2 + a3);
        acc += __shfl_xor(acc, 1, 64);          // combine the two halves
        float hnew = tanhf(bias + acc);         // both halves compute identically

        __syncthreads();                        // all LDS reads of h/hp done
        if (!half) {
            h_lds[j] = hnew;
            if (WRITE_ALL) out[(size_t)s * BB * HH + (size_t)b * HH + j] = hnew;
            else if (s == SS - 1) out[(size_t)b * HH + j] = hnew;
        }
        if (s + 1 < SS && tid < DP) hp[cur ^ 1][tid] = pn;
        __syncthreads();
        cur ^= 1;
    }
}

__global__ __launch_bounds__(128)
void fc_k(const float* __restrict__ hlast,   // (B,H)
          const float* __restrict__ fc_w,    // (NC,H)
          const float* __restrict__ fc_b,    // (NC)
          float* __restrict__ out)           // (B,NC)
{
    const int b = blockIdx.x;
    const int tid = threadIdx.x;
    __shared__ __align__(16) float h[HH];
    h[tid] = hlast[(size_t)b * HH + tid];
    __syncthreads();
    if (tid < NC) {
        float a = fc_b[tid];
        const float* wr = fc_w + tid * HH;
        #pragma unroll 4
        for (int k = 0; k < HH; ++k) a += h[k] * wr[k];
        out[(size_t)b * NC + tid] = a;
    }
}

extern "C" void kernel_launch(void* const* d_in, const int* in_sizes, int n_in,
                              void* d_out, int out_size, void* d_ws, size_t ws_size,
                              hipStream_t stream) {
    const float* x     = (const float*)d_in[0];   // (512,256,28)
    const float* w_ih0 = (const float*)d_in[1];   // (128,28)
    const float* w_hh0 = (const float*)d_in[2];   // (128,128)
    const float* b_ih0 = (const float*)d_in[3];
    const float* b_hh0 = (const float*)d_in[4];
    const float* w_ih  = (const float*)d_in[5];   // (3,128,128)
    const float* w_hh  = (const float*)d_in[6];   // (3,128,128)
    const float* b_ih  = (const float*)d_in[7];   // (3,128)
    const float* b_hh  = (const float*)d_in[8];
    const float* fc_w  = (const float*)d_in[9];   // (10,128)
    const float* fc_b  = (const float*)d_in[10];
    float* out = (float*)d_out;

    float* buf  = (float*)d_ws;                       // (S,B,H) fp32 = 64 MB
    float* hfin = buf + (size_t)SS * BB * HH;         // (B,H)

    // layer 0: x -> buf
    scan_k<28, true, true><<<BB, 256, 0, stream>>>(x, buf, w_ih0, w_hh0, b_ih0, b_hh0);
    // layers 1,2: buf -> buf (in-place)
    scan_k<128, false, true><<<BB, 256, 0, stream>>>(buf, buf,
        w_ih + 0 * HH * HH, w_hh + 0 * HH * HH, b_ih + 0 * HH, b_hh + 0 * HH);
    scan_k<128, false, true><<<BB, 256, 0, stream>>>(buf, buf,
        w_ih + 1 * HH * HH, w_hh + 1 * HH * HH, b_ih + 1 * HH, b_hh + 1 * HH);
    // layer 3: buf -> hfin (only final h needed)
    scan_k<128, false, false><<<BB, 256, 0, stream>>>(buf, hfin,
        w_ih + 2 * HH * HH, w_hh + 2 * HH * HH, b_ih + 2 * HH, b_hh + 2 * HH);
    // classifier
    fc_k<<<BB, 128, 0, stream>>>(hfin, fc_w, fc_b, out);
}